// Round 4
// baseline (88.394 us; speedup 1.0000x reference)
//
#include <hip/hip_runtime.h>
#include <hip/hip_bf16.h>

// Problem constants (match reference)
#define BB 4
#define CC 32
#define HH 64
#define WW 64
#define KK 64
#define PIX (HH * WW)      // 4096
#define NBC (BB * CC)      // 128 planes

// ---------------------------------------------------------------------------
// Numerics: reference's max-subtraction is pure stability; u~N(0,1), rf<=1
// bounds exp args by ~6 -> no overflow in f32. We compute (verified absmax 0):
//   inv_k = 1 / (1 + sum_{rf>0} exp(u*rf))
//   h[p]  = sum_k [rf_k>0] exp(u*rf_k) * inv_k ; out = 2x2 block max of h.
// Sparsity: rf is EXACTLY 0 outside the Gaussian support (~14% of plane).
// A per-k bbox (exact, recomputed on-device every call) lets both phases
// skip ~80% of loads/exps.
// ---------------------------------------------------------------------------

// Kernel 0: exact bbox of rf>0 per k. Grid = KK blocks x 256 thr.
__global__ __launch_bounds__(256) void rf_bbox(
        const float* __restrict__ rfs, int4* __restrict__ bbox) {
    const int k = blockIdx.x;
    const int t = threadIdx.x;
    const int l = t & 63;

    int minr = HH, maxr = -1, minc = WW, maxc = -1;
    const float4* r4 = (const float4*)(rfs + (size_t)k * PIX);
    #pragma unroll
    for (int i = 0; i < 4; ++i) {
        const float4 v = r4[t + 256 * i];
        const int px = 4 * (t + 256 * i);
        const int r = px >> 6, cbase = px & 63;
        const float vv[4] = {v.x, v.y, v.z, v.w};
        #pragma unroll
        for (int j = 0; j < 4; ++j) {
            if (vv[j] > 0.f) {
                minr = min(minr, r);       maxr = max(maxr, r);
                minc = min(minc, cbase + j); maxc = max(maxc, cbase + j);
            }
        }
    }
    #pragma unroll
    for (int off = 32; off > 0; off >>= 1) {
        minr = min(minr, __shfl_xor(minr, off, 64));
        maxr = max(maxr, __shfl_xor(maxr, off, 64));
        minc = min(minc, __shfl_xor(minc, off, 64));
        maxc = max(maxc, __shfl_xor(maxc, off, 64));
    }
    __shared__ int sb[4];
    if (t == 0) { sb[0] = HH; sb[1] = -1; sb[2] = WW; sb[3] = -1; }
    __syncthreads();
    if (l == 0) {
        atomicMin(&sb[0], minr); atomicMax(&sb[1], maxr);
        atomicMin(&sb[2], minc); atomicMax(&sb[3], maxc);
    }
    __syncthreads();
    if (t == 0) bbox[k] = make_int4(sb[0], sb[1], sb[2], sb[3]);
}

// Phase 1: one WAVE per (bc,k), bbox-restricted masked sum of exp(u*rf).
// Grid = NBC*KK/4 = 2048 blocks x 256 thr. float4 lanes: 16 col-groups x
// 4 row-slots per iteration; col groups outside bbox exec-masked off.
__global__ __launch_bounds__(256) void rf_phase1(
        const float* __restrict__ u,
        const float* __restrict__ rfs,
        const int4* __restrict__ bbox,
        float* __restrict__ inv) {
    const int w   = threadIdx.x >> 6;
    const int l   = threadIdx.x & 63;
    const int idx = blockIdx.x * 4 + w;        // (bc,k) pair id
    const int bc  = idx >> 6;
    const int k   = idx & 63;

    const int4 bb = bbox[k];                   // same addr across wave -> bcast
    const int colbase = (l & 15) * 4;
    const bool colact = (colbase + 3 >= bb.z) && (colbase <= bb.w);

    const float* rp = rfs + (size_t)k * PIX;
    const float* up = u + (size_t)bc * PIX;

    float s = 0.f;
    for (int r = bb.x + (l >> 4); r <= bb.y; r += 4) {
        if (colact) {
            const float4 rv = *(const float4*)(rp + r * WW + colbase);
            const float4 uv = *(const float4*)(up + r * WW + colbase);
            s += (rv.x > 0.f) ? __expf(uv.x * rv.x) : 0.f;
            s += (rv.y > 0.f) ? __expf(uv.y * rv.y) : 0.f;
            s += (rv.z > 0.f) ? __expf(uv.z * rv.z) : 0.f;
            s += (rv.w > 0.f) ? __expf(uv.w * rv.w) : 0.f;
        }
    }
    #pragma unroll
    for (int off = 32; off > 0; off >>= 1)
        s += __shfl_xor(s, off, 64);
    if (l == 0) inv[bc * KK + k] = 1.f / (1.f + s);
}

// Phase 2: one WAVE per (bc, row-pair); k-loop with wave-uniform bbox-row
// skip + per-lane predicated loads. Grid = NBC*8 blocks x 256 thr
// (block = bc x 8-row chunk; wave w = rows chunk*8+2w, +1). Pool via
// in-register fmax + shfl_xor(1). No barriers after the LDS preload.
__global__ __launch_bounds__(256) void rf_phase2(
        const float* __restrict__ u,
        const float* __restrict__ rfs,
        const int4* __restrict__ bbox,
        const float* __restrict__ inv,
        float* __restrict__ out) {
    const int bc    = blockIdx.x >> 3;
    const int chunk = blockIdx.x & 7;          // 8 rows
    const int t     = threadIdx.x;
    const int w     = t >> 6;
    const int l     = t & 63;
    const int R0    = chunk * 8 + 2 * w;       // wave-uniform row pair

    __shared__ float sinv[KK];
    __shared__ int4  sbb[KK];
    if (t < KK) { sinv[t] = inv[bc * KK + t]; sbb[t] = bbox[t]; }

    const float u0 = u[(size_t)bc * PIX + R0 * WW + l];
    const float u1 = u[(size_t)bc * PIX + (R0 + 1) * WW + l];
    __syncthreads();

    float h0 = 0.f, h1 = 0.f;
    #pragma unroll 4
    for (int k = 0; k < KK; ++k) {
        const int4 bb = sbb[k];
        if (bb.y < R0 || bb.x > R0 + 1) continue;   // wave-uniform skip
        const float fi = sinv[k];
        const bool colact = (l >= bb.z) && (l <= bb.w);
        const float* rp = rfs + (size_t)k * PIX + R0 * WW + l;
        if (colact && R0 >= bb.x && R0 <= bb.y) {
            const float rv = rp[0];
            h0 += (rv > 0.f) ? __expf(u0 * rv) * fi : 0.f;
        }
        if (colact && R0 + 1 >= bb.x && R0 + 1 <= bb.y) {
            const float rv = rp[WW];
            h1 += (rv > 0.f) ? __expf(u1 * rv) * fi : 0.f;
        }
    }

    const float v = fmaxf(h0, h1);
    const float o = fmaxf(v, __shfl_xor(v, 1, 64));
    if ((l & 1) == 0)
        out[(size_t)bc * (HH / 2) * (WW / 2) + (chunk * 4 + w) * 32 + (l >> 1)] = o;
}

extern "C" void kernel_launch(void* const* d_in, const int* in_sizes, int n_in,
                              void* d_out, int out_size, void* d_ws, size_t ws_size,
                              hipStream_t stream) {
    const float* u   = (const float*)d_in[0];
    const float* rfs = (const float*)d_in[1];
    float* out       = (float*)d_out;
    int4* bbox       = (int4*)d_ws;                       // 64 * 16 B
    float* inv       = (float*)((char*)d_ws + KK * sizeof(int4)); // 32 KB

    rf_bbox  <<<KK, 256, 0, stream>>>(rfs, bbox);
    rf_phase1<<<NBC * KK / 4, 256, 0, stream>>>(u, rfs, bbox, inv);
    rf_phase2<<<NBC * 8, 256, 0, stream>>>(u, rfs, bbox, inv, out);
}